// Round 1
// baseline (686.696 us; speedup 1.0000x reference)
//
#include <hip/hip_runtime.h>

#define BTOT   131072
#define INDIM  128
#define OUTDIM 512
#define VBS    128
#define NCHUNK (BTOT / VBS)   // 1024
#define NITER  10             // Michelot iterations (converges in ~4-5 from max-1)
#define EPS    1e-5f

typedef _Float16 half8  __attribute__((ext_vector_type(8)));
typedef float    floatx4 __attribute__((ext_vector_type(4)));

// ---------------------------------------------------------------------------
// Kernel 1: convert W [512x128] fp32 -> fp16 into workspace (row-major [o][k])
// ---------------------------------------------------------------------------
__global__ void w_to_half_kernel(const float* __restrict__ W,
                                 _Float16* __restrict__ Wh) {
    int i = blockIdx.x * blockDim.x + threadIdx.x;   // float4 index, 0..16383
    const float4 v = ((const float4*)W)[i];
    union { _Float16 h[4]; uint2 u; } p;
    p.h[0] = (_Float16)v.x; p.h[1] = (_Float16)v.y;
    p.h[2] = (_Float16)v.z; p.h[3] = (_Float16)v.w;
    ((uint2*)Wh)[i] = p.u;
}

// ---------------------------------------------------------------------------
// Kernel 2: fused GEMM(fp16 MFMA) + GhostBN + priors + sparsemax
// One block = one virtual batch (128 rows x 512 cols). 8 waves, each wave owns
// 16 rows x 512 cols: 32 col-tiles of 16x16x32 MFMA, acc[t] layout:
//   col = t*16 + (lane&15), row (within wave) = (lane>>4)*4 + reg
// ---------------------------------------------------------------------------
__launch_bounds__(512)
__global__ void fused_kernel(const float* __restrict__ priors,
                             const float* __restrict__ feat,
                             const _Float16* __restrict__ Wh,
                             const float* __restrict__ gamma,
                             const float* __restrict__ beta,
                             float* __restrict__ out)
{
    __shared__ float lds_sum[8][OUTDIM];
    __shared__ float lds_sq [8][OUTDIM];
    __shared__ float lds_a[OUTDIM];
    __shared__ float lds_b[OUTDIM];

    const int tid  = threadIdx.x;
    const int w    = tid >> 6;      // wave 0..7
    const int lane = tid & 63;
    const int i16  = lane & 15;
    const int quad = lane >> 4;     // 0..3
    const int row0 = blockIdx.x * VBS + w * 16;   // wave's first global row

    // ---- load A fragments (fp32 global -> fp16 regs) ----
    // A operand layout: A[m = lane&15][k = quad*8 + j], j=0..7, per 32-wide k-tile
    half8 afrag[4];
    {
        const float* ap = feat + (size_t)(row0 + i16) * INDIM + quad * 8;
        #pragma unroll
        for (int kt = 0; kt < 4; ++kt) {
            float4 v0 = *(const float4*)(ap + kt * 32);
            float4 v1 = *(const float4*)(ap + kt * 32 + 4);
            half8 h;
            h[0]=(_Float16)v0.x; h[1]=(_Float16)v0.y; h[2]=(_Float16)v0.z; h[3]=(_Float16)v0.w;
            h[4]=(_Float16)v1.x; h[5]=(_Float16)v1.y; h[6]=(_Float16)v1.z; h[7]=(_Float16)v1.w;
            afrag[kt] = h;
        }
    }

    // ---- GEMM: C[b][o] = sum_k feat[b][k] * W[o][k] ----
    // B operand layout: B[k = quad*8+j][n = lane&15] = W[tile*16 + n][k]
    floatx4 acc[32];
    {
        // pointer in half8 (16B) units; alignment: i16*128 halves = 256B, quad*8 = 16B
        const half8* wp0 = (const half8*)(Wh + (size_t)i16 * INDIM + quad * 8);
        #pragma unroll
        for (int t = 0; t < 32; ++t) {
            floatx4 c = {0.f, 0.f, 0.f, 0.f};
            #pragma unroll
            for (int kt = 0; kt < 4; ++kt) {
                half8 b = wp0[t * 256 + kt * 4];   // t*16 rows * 128 halves/row /8 ; kt*32 halves /8
                c = __builtin_amdgcn_mfma_f32_16x16x32_f16(afrag[kt], b, c, 0, 0, 0);
            }
            acc[t] = c;
        }
    }

    // ---- Ghost BN statistics: per-column mean/var over the 128 rows ----
    #pragma unroll
    for (int t = 0; t < 32; ++t) {
        floatx4 v = acc[t];
        float s = v.x + v.y + v.z + v.w;
        float q = v.x*v.x + v.y*v.y + v.z*v.z + v.w*v.w;
        s += __shfl_xor(s, 16); q += __shfl_xor(q, 16);
        s += __shfl_xor(s, 32); q += __shfl_xor(q, 32);
        if (quad == 0) {
            lds_sum[w][t * 16 + i16] = s;
            lds_sq [w][t * 16 + i16] = q;
        }
    }
    __syncthreads();
    {
        // 512 threads: one column each
        float s = 0.f, q = 0.f;
        #pragma unroll
        for (int j = 0; j < 8; ++j) { s += lds_sum[j][tid]; q += lds_sq[j][tid]; }
        float mean = s * (1.0f / VBS);
        float var  = q * (1.0f / VBS) - mean * mean;
        float rstd = 1.0f / sqrtf(var + EPS);
        float a = gamma[tid] * rstd;
        float b = beta[tid] - mean * a;
        lds_a[tid] = a;
        lds_b[tid] = b;
    }
    __syncthreads();

    // ---- normalize + multiply priors ----
    const float* pbase = priors + (size_t)(row0 + quad * 4) * OUTDIM + i16;
    #pragma unroll
    for (int t = 0; t < 32; ++t) {
        const int col = t * 16 + i16;
        const float a = lds_a[col];
        const float b = lds_b[col];
        float p0 = pbase[t * 16];
        float p1 = pbase[OUTDIM + t * 16];
        float p2 = pbase[2 * OUTDIM + t * 16];
        float p3 = pbase[3 * OUTDIM + t * 16];
        floatx4 v = acc[t];
        v.x = (v.x * a + b) * p0;
        v.y = (v.y * a + b) * p1;
        v.z = (v.z * a + b) * p2;
        v.w = (v.w * a + b) * p3;
        acc[t] = v;
    }

    // ---- sparsemax per row (wave-local; rows quad*4+r, 16 lanes/row) ----
    float mx[4] = {-3.4e38f, -3.4e38f, -3.4e38f, -3.4e38f};
    #pragma unroll
    for (int t = 0; t < 32; ++t) {
        floatx4 v = acc[t];
        mx[0] = fmaxf(mx[0], v.x); mx[1] = fmaxf(mx[1], v.y);
        mx[2] = fmaxf(mx[2], v.z); mx[3] = fmaxf(mx[3], v.w);
    }
    #pragma unroll
    for (int r = 0; r < 4; ++r) {
        mx[r] = fmaxf(mx[r], __shfl_xor(mx[r], 1));
        mx[r] = fmaxf(mx[r], __shfl_xor(mx[r], 2));
        mx[r] = fmaxf(mx[r], __shfl_xor(mx[r], 4));
        mx[r] = fmaxf(mx[r], __shfl_xor(mx[r], 8));
    }
    // Michelot fixed-point from tau0 = max - 1 (support subset guaranteed)
    float tau[4] = {mx[0] - 1.0f, mx[1] - 1.0f, mx[2] - 1.0f, mx[3] - 1.0f};
    for (int it = 0; it < NITER; ++it) {
        float s[4] = {0.f, 0.f, 0.f, 0.f};
        float c[4] = {0.f, 0.f, 0.f, 0.f};
        #pragma unroll
        for (int t = 0; t < 32; ++t) {
            floatx4 v = acc[t];
            if (v.x > tau[0]) { s[0] += v.x; c[0] += 1.0f; }
            if (v.y > tau[1]) { s[1] += v.y; c[1] += 1.0f; }
            if (v.z > tau[2]) { s[2] += v.z; c[2] += 1.0f; }
            if (v.w > tau[3]) { s[3] += v.w; c[3] += 1.0f; }
        }
        #pragma unroll
        for (int r = 0; r < 4; ++r) {
            s[r] += __shfl_xor(s[r], 1); c[r] += __shfl_xor(c[r], 1);
            s[r] += __shfl_xor(s[r], 2); c[r] += __shfl_xor(c[r], 2);
            s[r] += __shfl_xor(s[r], 4); c[r] += __shfl_xor(c[r], 4);
            s[r] += __shfl_xor(s[r], 8); c[r] += __shfl_xor(c[r], 8);
            tau[r] = (s[r] - 1.0f) * __builtin_amdgcn_rcpf(c[r]);
        }
    }

    // ---- write output: clip(x - tau, 0) ----
    float* obase = out + (size_t)(row0 + quad * 4) * OUTDIM + i16;
    #pragma unroll
    for (int t = 0; t < 32; ++t) {
        floatx4 v = acc[t];
        obase[t * 16]              = fmaxf(v.x - tau[0], 0.f);
        obase[OUTDIM + t * 16]     = fmaxf(v.y - tau[1], 0.f);
        obase[2 * OUTDIM + t * 16] = fmaxf(v.z - tau[2], 0.f);
        obase[3 * OUTDIM + t * 16] = fmaxf(v.w - tau[3], 0.f);
    }
}

// ---------------------------------------------------------------------------
extern "C" void kernel_launch(void* const* d_in, const int* in_sizes, int n_in,
                              void* d_out, int out_size, void* d_ws, size_t ws_size,
                              hipStream_t stream) {
    const float* priors = (const float*)d_in[0];
    const float* feat   = (const float*)d_in[1];
    const float* W      = (const float*)d_in[2];
    const float* gamma  = (const float*)d_in[3];
    const float* beta   = (const float*)d_in[4];
    float* out = (float*)d_out;
    _Float16* Wh = (_Float16*)d_ws;   // 512*128*2 = 128 KB

    // W fp32 -> fp16 (65536 elems = 16384 float4)
    hipLaunchKernelGGL(w_to_half_kernel, dim3(64), dim3(256), 0, stream, W, Wh);
    // fused pipeline: one block per virtual batch of 128 rows
    hipLaunchKernelGGL(fused_kernel, dim3(NCHUNK), dim3(512), 0, stream,
                       priors, feat, Wh, gamma, beta, out);
}